// Round 22
// baseline (129.760 us; speedup 1.0000x reference)
//
#include <hip/hip_runtime.h>
#include <hip/hip_bf16.h>
#include <math.h>

#define BB 8
#define NMODE 24

typedef __attribute__((ext_vector_type(8))) short bf16x8;
typedef __attribute__((ext_vector_type(4))) short bf16x4;
typedef __attribute__((ext_vector_type(4))) float f32x4;

#define MFMA32(a,b,c) __builtin_amdgcn_mfma_f32_16x16x32_bf16(a,b,c,0,0,0)

#if __has_builtin(__builtin_amdgcn_mfma_f32_16x16x16bf16_1k)
#define MFMA16(a,b,c) __builtin_amdgcn_mfma_f32_16x16x16bf16_1k(a,b,c,0,0,0)
#else
static __device__ __forceinline__ f32x4 MFMA16(bf16x4 a, bf16x4 b, f32x4 c){
    f32x4 d;
    asm("v_mfma_f32_16x16x16_bf16 %0, %1, %2, %3" : "=v"(d) : "v"(a), "v"(b), "v"(c));
    return d;
}
#endif

// packed f32->bf16 RNE via compiler intrinsic (memcpy, NOT bit_cast: round-4 lesson)
__device__ __forceinline__ unsigned pk2(float lo, float hi){
    __hip_bfloat162 h = __float22bfloat162_rn(make_float2(lo, hi));
    unsigned u; __builtin_memcpy(&u, &h, 4);
    return u;
}
__device__ __forceinline__ short f2b(float f){
    unsigned u = pk2(f, f);
    return (short)u;
}
__device__ __forceinline__ float b2f(short s){
    unsigned u = ((unsigned)(unsigned short)s) << 16;
    return __builtin_bit_cast(float, u);
}
__device__ __forceinline__ bf16x4 cvt4(f32x4 v){
    uint2 t; t.x = pk2(v[0], v[1]); t.y = pk2(v[2], v[3]);
    return __builtin_bit_cast(bf16x4, t);
}
__device__ __forceinline__ bf16x8 cvt8(float4 a, float4 b){
    uint4 t; t.x = pk2(a.x, a.y); t.y = pk2(a.z, a.w);
    t.z = pk2(b.x, b.y); t.w = pk2(b.z, b.w);
    return __builtin_bit_cast(bf16x8, t);
}
// tanh-gelu: v - v/(1+exp(2u)); exp2-based, ~8 VALU ops. NaN-safe.
__device__ __forceinline__ float gelu_f(float v) {
    float v2  = v * v;
    float arg = v * fmaf(0.10294294f, v2, 2.30220795f);
    float s   = __builtin_amdgcn_exp2f(arg);
    float rc  = __builtin_amdgcn_rcpf(1.0f + s);
    return v - v * rc;
}

// ======== kern0: precompute bf16 tables (Kp/basis sections split fine) ========
__global__ __launch_bounds__(256) void kern0(
    const float* __restrict__ Lw1, const float* __restrict__ Lb1, const float* __restrict__ Lw2,
    const float* __restrict__ Gw1, const float* __restrict__ Gb1, const float* __restrict__ Gw2,
    const float* __restrict__ uw,
    const float* __restrict__ Wuw, const float* __restrict__ Huw,
    const float* __restrict__ Msw, const float* __restrict__ Msb,
    const float* __restrict__ ow,  const float* __restrict__ ob,
    const float* __restrict__ Wub,
    const float* __restrict__ k1r, const float* __restrict__ k1i,
    const float* __restrict__ k2r, const float* __restrict__ k2i,
    short* __restrict__ G1a, short* __restrict__ L1a,
    short* __restrict__ G2T, short* __restrict__ L2T,
    short* __restrict__ WuT, short* __restrict__ HuT,
    short* __restrict__ owT, short* __restrict__ uwT, short* __restrict__ MsA,
    short* __restrict__ basisW, short* __restrict__ basis2P,
    short* __restrict__ basisH1, short* __restrict__ basisH3,
    short* __restrict__ Kp, float* __restrict__ obP)
{
    const int bid = blockIdx.x, t = threadIdx.x;
    const float tp = 6.28318530717958648f/256.f;
    if (bid == 0){
        for (int idx=t; idx<1024; idx+=256){
            int o = idx>>5, c = idx&31;
            WuT[o*32+c] = f2b(Wuw[c*32+o]);
        }
    } else if (bid == 1){
        for (int idx=t; idx<1024; idx+=256){
            int o = idx>>5, c = idx&31;
            HuT[o*32+c] = f2b(Huw[c*32+o]);
        }
    } else if (bid == 2){
        for (int idx=t; idx<1024; idx+=256){
            int hd = idx>>4, k2 = idx&15;
            G1a[idx] = f2b(k2<4 ? Gw1[k2*64+hd] : (k2==4 ? Gb1[hd] : 0.f));
            L1a[idx] = f2b(k2<4 ? Lw1[k2*64+hd] : (k2==4 ? Lb1[hd] : 0.f));
        }
    } else if (bid == 3){
        for (int idx=t; idx<2048; idx+=256){ int o=idx>>6, m=idx&63; G2T[idx]=f2b(Gw2[m*32+o]); }
    } else if (bid == 4){
        for (int idx=t; idx<2048; idx+=256){ int o=idx>>6, m=idx&63; L2T[idx]=f2b(Lw2[m*32+o]); }
    } else if (bid == 5){
        for (int idx=t; idx<1024; idx+=256){
            int o=idx>>5, c=idx&31;
            owT[idx]=f2b(ow[c*32+o]);
            uwT[idx]=f2b(uw[c*32+o]);
        }
    } else if (bid == 6){
        for (int idx=t; idx<512; idx+=256){
            int o=idx>>4, k2=idx&15;
            MsA[idx]=f2b(k2<4 ? Msw[k2*32+o] : (k2==4 ? Msb[o] : 0.f));
        }
        if (t < 32){
            float s = ob[t];
            for (int c=0;c<32;c++) s += Wub[c]*ow[c*32+t];
            obP[t] = s;
        }
    } else if (bid < 15){
        int base=(bid-7)*1024;
        for (int i=t; i<1024; i+=256){
            int idx=base+i; int m=idx>>8, w=idx&255;
            float v=0.f;
            if (m<12)       v = cosf(tp*(float)((m*w)&255));
            else if (m<24)  v = sinf(tp*(float)(((m-12)*w)&255));
            basisW[idx]=f2b(v);
        }
    } else if (bid < 23){
        int base=(bid-15)*1024;
        for (int i=t; i<1024; i+=256){
            int idx=base+i; int w=idx>>5, k=idx&31;
            float v=0.f;
            if (k<24){ int m=k>>1; float a=tp*(float)((m*w)&255); v=(k&1)? -sinf(a):cosf(a); }
            basis2P[idx]=f2b(v);
        }
    } else if (bid < 35){
        // basisH1: 12 blocks x 1024
        int base=(bid-23)*1024;
        for (int i=t; i<1024; i+=256){
            int idx=base+i; int m = idx>>8, h = idx&255;
            int mm = m % 24;
            int ia = (mm<12) ? mm : 232+mm;
            float a = tp*(float)((ia*h)&255);
            basisH1[idx] = f2b(m<24 ? cosf(a) : sinf(a));
        }
    } else if (bid < 51){
        // basisH3: 16 blocks x 1024
        int base=(bid-35)*1024;
        for (int i=t; i<1024; i+=256){
            int idx=base+i; int h = idx>>6, k = idx&63;
            float v = 0.f;
            if (k < 48){
                int mm = k % 24;
                int ia = (mm<12) ? mm : 232+mm;
                float a = tp*(float)((ia*h)&255);
                v = (k<24) ? cosf(a) : sinf(a);
            }
            basisH3[idx] = f2b(v);
        }
    } else {
        // Kp: 288 blocks x 1024 entries (fine split for gather-latency hiding)
        int base=(bid-51)*1024;
        for (int i=t; i<1024; i+=256){
            int pid = base + i;
            int o = pid & 31, c = (pid>>5) & 31;
            int rest = pid >> 10;
            int ii = rest % 24, jj = rest / 24;
            int iis = (ii<12) ? ii : ii-12;
            const float* wr = (ii<12) ? k1r : k2r;
            const float* wi = (ii<12) ? k1i : k2i;
            size_t widx = ((size_t)(c*32 + o)*12 + iis)*12 + jj;
            float sc = (jj==0 ? 1.f : 2.f) / 65536.f;
            Kp[2*pid]   = f2b(wr[widx] * sc);
            Kp[2*pid+1] = f2b(wi[widx] * sc);
        }
    }
}

// Forward layout in d_out per block bh (region 32 KB = 16384 shorts):
//   u slot s = nt*2+mt (0..7), G slot s = 8+nt*2+mt (8..15)
//   addr_shorts = bh*16384 + s*1024 + tid*4 (bf16x4/thread)

// ======== kernAG: role-split. blocks<NA: A-role; blocks>=NA: G-role ========
__global__ __launch_bounds__(256, 6) void kernAG(
    const float* __restrict__ x, const float* __restrict__ kk,
    const float* __restrict__ Lb2, const float* __restrict__ ubv,
    const float* __restrict__ Gb2,
    const short* __restrict__ L1a, const short* __restrict__ L2T,
    const short* __restrict__ G1a, const short* __restrict__ G2T,
    const short* __restrict__ uwT, const short* __restrict__ MsA,
    const short* __restrict__ basisW, float* __restrict__ A1,
    float* __restrict__ outw)
{
    __shared__ short vT[32*264];   // A-role only
    const int tid = threadIdx.x, l = tid&63, wv = tid>>6;
    const int q = l>>4, r = l&15;
    const f32x4 z4 = {0.f,0.f,0.f,0.f};

    if (blockIdx.x >= (unsigned)(BB*256)){
        // ---------------- G-role ----------------
        const int bh = blockIdx.x - BB*256;
        short* ug = (short*)outw + (size_t)bh*16384;

        bf16x4 ga[4], g2f[2][4];
        #pragma unroll
        for (int mt=0; mt<4; mt++) ga[mt] = *(const bf16x4*)(G1a + (r+16*mt)*16 + 4*q);
        #pragma unroll
        for (int mt=0; mt<2; mt++)
            #pragma unroll
            for (int ks=0; ks<4; ks++)
                g2f[mt][ks] = *(const bf16x4*)(G2T + (r+16*mt)*64 + 16*ks + 4*q);
        f32x4 gb2v[2];
        #pragma unroll
        for (int mt=0; mt<2; mt++) gb2v[mt] = *(const f32x4*)(Gb2 + 16*mt + 4*q);

        bf16x4 kB[4];
        #pragma unroll
        for (int nt=0; nt<4; nt++){
            const int p = wv*64 + nt*16 + r;
            bf16x4 t = {0,0,0,0};
            if (q==0){
                float4 k4 = *(const float4*)(kk + ((size_t)bh*256 + p)*4);
                uint2 pkk; pkk.x = pk2(k4.x, k4.y); pkk.y = pk2(k4.z, k4.w);
                t = __builtin_bit_cast(bf16x4, pkk);
            } else if (q==1){ t[0] = (short)0x3F80; }
            kB[nt] = t;
        }

        bf16x4 hidG[4][4];
        #pragma unroll
        for (int nt=0; nt<4; nt++)
            #pragma unroll
            for (int mt=0; mt<4; mt++){
                f32x4 acc = MFMA16(ga[mt], kB[nt], z4);
                f32x4 g;
                #pragma unroll
                for (int i=0;i<4;i++) g[i]=gelu_f(acc[i]);
                hidG[nt][mt] = cvt4(g);
            }

        #pragma unroll
        for (int nt=0; nt<4; nt++){
            #pragma unroll
            for (int mt=0; mt<2; mt++){
                f32x4 aG  = MFMA16(g2f[mt][0], hidG[nt][0], gb2v[mt]);
                f32x4 aG2 = MFMA16(g2f[mt][1], hidG[nt][1], z4);
                aG  = MFMA16(g2f[mt][2], hidG[nt][2], aG);
                aG2 = MFMA16(g2f[mt][3], hidG[nt][3], aG2);
                f32x4 gs;
                #pragma unroll
                for (int rg=0; rg<4; rg++) gs[rg] = aG[rg] + aG2[rg];
                *(bf16x4*)(ug + (8 + nt*2+mt)*1024 + tid*4) = cvt4(gs);
            }
        }
        return;
    }

    // ---------------- A-role ----------------
    const int bh = blockIdx.x, b = bh>>8, h = bh&255;
    short* ug = (short*)outw + (size_t)bh*16384;

    bf16x4 la[4], ma[2], l2f[2][4];
    bf16x8 ua8[2];
    #pragma unroll
    for (int mt=0; mt<4; mt++) la[mt] = *(const bf16x4*)(L1a + (r+16*mt)*16 + 4*q);
    #pragma unroll
    for (int mt=0; mt<2; mt++){
        ma[mt]  = *(const bf16x4*)(MsA + (r+16*mt)*16 + 4*q);
        ua8[mt] = *(const bf16x8*)(uwT + (r+16*mt)*32 + 8*q);
        #pragma unroll
        for (int ks=0; ks<4; ks++)
            l2f[mt][ks] = *(const bf16x4*)(L2T + (r+16*mt)*64 + 16*ks + 4*q);
    }
    f32x4 lb2v[2], ubv4[2];
    #pragma unroll
    for (int mt=0; mt<2; mt++){
        lb2v[mt] = *(const f32x4*)(Lb2 + 16*mt + 4*q);
        ubv4[mt] = *(const f32x4*)(ubv + 16*mt + 4*q);
    }

    #pragma unroll
    for (int nt=0; nt<4; nt++){
        const int p = wv*64 + nt*16 + r;
        const float* xp = x + ((size_t)bh*256 + p)*32 + 8*q;
        float4 x0 = *(const float4*)xp;
        float4 x1 = *(const float4*)(xp + 4);
        bf16x8 xB8 = cvt8(x0, x1);
        bf16x4 kB = {0,0,0,0};
        if (q==0){
            float4 k4 = *(const float4*)(kk + ((size_t)bh*256 + p)*4);
            uint2 pkk; pkk.x = pk2(k4.x, k4.y); pkk.y = pk2(k4.z, k4.w);
            kB = __builtin_bit_cast(bf16x4, pkk);
        } else if (q==1){ kB[0] = (short)0x3F80; }

        bf16x4 hidL[4];
        #pragma unroll
        for (int mt=0; mt<4; mt++){
            f32x4 accL = MFMA16(la[mt], kB, z4);
            f32x4 gl;
            #pragma unroll
            for (int i=0;i<4;i++) gl[i]=gelu_f(accL[i]);
            hidL[mt] = cvt4(gl);
        }
        #pragma unroll
        for (int mt=0; mt<2; mt++){
            f32x4 aU = MFMA32(ua8[mt], xB8, ubv4[mt]);
            // forward u (coalesced slot store)
            *(bf16x4*)(ug + (nt*2+mt)*1024 + tid*4) = cvt4(aU);
            f32x4 aM = MFMA16(ma[mt], kB, z4);
            f32x4 aL  = MFMA16(l2f[mt][0], hidL[0], lb2v[mt]);
            f32x4 aL2 = MFMA16(l2f[mt][1], hidL[1], z4);
            aL  = MFMA16(l2f[mt][2], hidL[2], aL);
            aL2 = MFMA16(l2f[mt][3], hidL[3], aL2);
            f32x4 vv;
            #pragma unroll
            for (int rg=0; rg<4; rg++) vv[rg] = (aL[rg]+aL2[rg]) * aU[rg] + aM[rg];
            bf16x4 vb = cvt4(vv);
            #pragma unroll
            for (int rg=0; rg<4; rg++)
                vT[(16*mt + 4*q + rg)*264 + p] = vb[rg];
        }
    }
    __syncthreads();

    // w-DFT
    const int mt2 = wv>>1, nt2 = wv&1;
    f32x4 accD = z4;
    #pragma unroll
    for (int ks=0; ks<8; ks++){
        bf16x8 av = *(const bf16x8*)(basisW + (r+16*mt2)*256 + 32*ks + 8*q);
        bf16x8 bv = *(const bf16x8*)(&vT[(r+16*nt2)*264 + 32*ks + 8*q]);
        accD = MFMA32(av, bv, accD);
    }
    #pragma unroll
    for (int rg=0; rg<4; rg++){
        int mode = 16*mt2 + 4*q + rg;
        int ch = r + 16*nt2;
        if (mode < 12)
            A1[((size_t)(b*12+mode)*256 + h)*64 + ch*2] = accD[rg];
        else if (mode < 24)
            A1[((size_t)(b*12+mode-12)*256 + h)*64 + ch*2 + 1] = -accD[rg];
    }
}

// ======== kernC1: per (b,j): LDS-transposed MFMA h-DFT + spectral multiply ========
__global__ __launch_bounds__(512) void kernC1(
    const float* __restrict__ A1, const short* __restrict__ basisH1,
    const short* __restrict__ Kp, short* __restrict__ SBg)
{
    __shared__ short AT[64*264];
    __shared__ float C1L[48*66];
    const int bj = blockIdx.x;
    const int j  = bj % 12;
    const int tid = threadIdx.x, l = tid&63;
    const int w = tid>>6;
    const int q = l>>4, r = l&15;
    const f32x4 z4 = {0.f,0.f,0.f,0.f};

    {
        const float* Ag = A1 + (size_t)bj*16384;
        for (int i = tid; i < 4096; i += 512){
            float4 v = *(const float4*)(Ag + i*4);
            int hh = (i*4) >> 6;
            int cc = (i*4) & 63;
            AT[(cc+0)*264 + hh] = f2b(v.x);
            AT[(cc+1)*264 + hh] = f2b(v.y);
            AT[(cc+2)*264 + hh] = f2b(v.z);
            AT[(cc+3)*264 + hh] = f2b(v.w);
        }
    }
    __syncthreads();

    {
        const int nt  = w & 3;
        const int nmt = (w < 4) ? 2 : 1;
        const int mt0 = (w < 4) ? 0 : 2;
        f32x4 acc[2] = {z4, z4};
        #pragma unroll
        for (int ks=0; ks<8; ks++){
            bf16x8 bv = *(const bf16x8*)(AT + (nt*16 + r)*264 + ks*32 + q*8);
            #pragma unroll
            for (int mi=0; mi<2; mi++){
                if (mi < nmt){
                    bf16x8 av = *(const bf16x8*)(basisH1 + (r + 16*(mt0+mi))*256 + ks*32 + q*8);
                    acc[mi] = MFMA32(av, bv, acc[mi]);
                }
            }
        }
        #pragma unroll
        for (int mi=0; mi<2; mi++){
            if (mi < nmt){
                #pragma unroll
                for (int rg=0; rg<4; rg++)
                    C1L[(16*(mt0+mi) + 4*q + rg)*66 + 16*nt + r] = acc[mi][rg];
            }
        }
    }
    __syncthreads();

    {
        const int o = tid & 31, g = tid >> 5;
        short* SB = SBg + (size_t)bj*4096;
        #pragma unroll
        for (int half=0; half<2; half++){
            int i = g + 16*half;
            if (i < 24){
                float Sre=0.f, Sim=0.f;
                const short* kp = Kp + ((size_t)(j*24 + i)*32)*64 + 2*o;
                #pragma unroll 4
                for (int c=0; c<32; c++){
                    float vr = C1L[i*66 + 2*c]     + C1L[(24+i)*66 + 2*c+1];
                    float vi = C1L[i*66 + 2*c + 1] - C1L[(24+i)*66 + 2*c];
                    short2 kv = *(const short2*)(kp + c*64);
                    float kr = b2f(kv.x), ki = b2f(kv.y);
                    Sre += vr*kr - vi*ki;
                    Sim += vr*ki + vi*kr;
                }
                SB[o*64 + i]           = f2b(Sre);
                SB[o*64 + 24 + i]      = f2b(-Sim);
                SB[2048 + o*64 + i]    = f2b(Sim);
                SB[2048 + o*64 + 24+i] = f2b(Sre);
            }
        }
        int o2 = (tid >> 4) & 31, kz = 48 + (tid & 15);
        SB[o2*64 + kz] = 0;
        SB[2048 + o2*64 + kz] = 0;
    }
}

// ======== kernC2: inverse h-DFT for ALL j, Hub folded into k=0, dense Tp dump ========
__global__ __launch_bounds__(256) void kernC2(
    const short* __restrict__ basisH3, const short* __restrict__ SBg,
    const float* __restrict__ Hub, short* __restrict__ Tp)
{
    __shared__ __align__(16) short Tt[16*1024];
    const int bid = blockIdx.x;
    const int b = bid >> 4, ht = bid & 15;
    const int tid = threadIdx.x, l = tid&63, w = tid>>6;
    const int q = l>>4, r = l&15;
    const f32x4 z4 = {0.f,0.f,0.f,0.f};

    for (int idx = tid; idx < 512; idx += 256){
        int hh = idx >> 5, o = idx & 31;
        #pragma unroll
        for (int kkz=0; kkz<8; kkz++) Tt[(hh*32+o)*32 + 24 + kkz] = 0;
    }

    bf16x8 af[2];
    #pragma unroll
    for (int ks=0; ks<2; ks++)
        af[ks] = *(const bf16x8*)(basisH3 + (ht*16 + r)*64 + ks*32 + q*8);

    #pragma unroll
    for (int jj=0; jj<3; jj++){
        int j = w*3 + jj;
        const short* SB = SBg + (size_t)(b*12 + j)*4096;
        #pragma unroll
        for (int nt=0; nt<2; nt++){
            f32x4 aRe = z4, aIm = z4;
            #pragma unroll
            for (int ks=0; ks<2; ks++){
                bf16x8 b1 = *(const bf16x8*)(SB + (16*nt + r)*64 + ks*32 + q*8);
                bf16x8 b2 = *(const bf16x8*)(SB + 2048 + (16*nt + r)*64 + ks*32 + q*8);
                aRe = MFMA32(af[ks], b1, aRe);
                aIm = MFMA32(af[ks], b2, aIm);
            }
            if (j == 0){
                float hb = Hub[16*nt + r];
                #pragma unroll
                for (int rg=0; rg<4; rg++) aRe[rg] -= hb;
            }
            #pragma unroll
            for (int rg=0; rg<4; rg++){
                int hl = 4*q + rg, o = 16*nt + r;
                *(unsigned*)&Tt[(hl*32 + o)*32 + 2*j] = pk2(aRe[rg], aIm[rg]);
            }
        }
    }
    __syncthreads();

    short* dst = Tp + (size_t)(b*256 + ht*16)*1024;
    #pragma unroll
    for (int it=0; it<8; it++){
        int off = (tid + it*256)*8;
        *(int4*)(dst + off) = *(const int4*)&Tt[off];
    }
}

// ======== kernD: consumer — u and G from d_out slots ========
__global__ __launch_bounds__(256, 4) void kernD(
    const float* __restrict__ obP,
    const short* __restrict__ WuT, const short* __restrict__ HuT,
    const short* __restrict__ owT, const short* __restrict__ basis2P,
    const short* __restrict__ Tp, float* out)
{
    const int bh = blockIdx.x;
    const int tid = threadIdx.x, l = tid&63, wv = tid>>6;
    const int q = l>>4, r = l&15;
    const f32x4 z4 = {0.f,0.f,0.f,0.f};
    const short* ug = (const short*)out + (size_t)bh*16384;

    // ---- pre-barrier: u+G slot loads (alias out!) + fragments ----
    bf16x4 uB[4][2], Gf[4][2];
    bf16x8 bb8[4];
    #pragma unroll
    for (int nt=0; nt<4; nt++){
        const int p = wv*64 + nt*16 + r;
        #pragma unroll
        for (int ks=0; ks<2; ks++){
            uB[nt][ks] = *(const bf16x4*)(ug + (nt*2+ks)*1024 + tid*4);
            Gf[nt][ks] = *(const bf16x4*)(ug + (8 + nt*2+ks)*1024 + tid*4);
        }
        bb8[nt] = *(const bf16x8*)(basis2P + p*32 + 8*q);
    }
    bf16x8 tp8[2];
    bf16x4 wuf[2][2], huf[2][2], owf[2][2];
    f32x4 obv2[2];
    #pragma unroll
    for (int mt=0; mt<2; mt++){
        tp8[mt] = *(const bf16x8*)(Tp + (size_t)bh*1024 + (r+16*mt)*32 + 8*q);
        #pragma unroll
        for (int ks=0; ks<2; ks++){
            wuf[mt][ks] = *(const bf16x4*)(WuT + (r+16*mt)*32 + 16*ks + 4*q);
            huf[mt][ks] = *(const bf16x4*)(HuT + (r+16*mt)*32 + 16*ks + 4*q);
            owf[mt][ks] = *(const bf16x4*)(owT + (r+16*mt)*32 + 16*ks + 4*q);
        }
        obv2[mt] = *(const f32x4*)(obP + 16*mt + 4*q);
    }
    __syncthreads();   // drains loads before any out-store

    #pragma unroll
    for (int nt=0; nt<4; nt++){
        const int p = wv*64 + nt*16 + r;
        bf16x4 bornB[2];
        #pragma unroll
        for (int mt=0; mt<2; mt++){
            f32x4 aFv = MFMA32(tp8[mt], bb8[nt], z4);          // includes -Hub fold
            f32x4 aHu = MFMA16(huf[mt][0], uB[nt][0], z4);
            aHu = MFMA16(huf[mt][1], uB[nt][1], aHu);
            f32x4 aW  = MFMA16(wuf[mt][0], uB[nt][0], z4);
            aW  = MFMA16(wuf[mt][1], uB[nt][1], aW);
            f32x4 brn;
            #pragma unroll
            for (int rg=0; rg<4; rg++)
                brn[rg] = aW[rg] - b2f(Gf[nt][mt][rg]) * (aHu[rg] - aFv[rg]);
            bornB[mt] = cvt4(brn);
        }
        #pragma unroll
        for (int mt=0; mt<2; mt++){
            f32x4 aO = MFMA16(owf[mt][0], bornB[0], obv2[mt]); // includes Wub@ow fold
            aO = MFMA16(owf[mt][1], bornB[1], aO);
            float4 res;
            res.x = gelu_f(aO[0]);
            res.y = gelu_f(aO[1]);
            res.z = gelu_f(aO[2]);
            res.w = gelu_f(aO[3]);
            *(float4*)(out + ((size_t)bh*256 + p)*32 + 16*mt + 4*q) = res;
        }
    }
}

extern "C" void kernel_launch(void* const* d_in, const int* in_sizes, int n_in,
                              void* d_out, int out_size, void* d_ws, size_t ws_size,
                              hipStream_t stream)
{
    const float* x   = (const float*)d_in[0];
    const float* kk  = (const float*)d_in[1];
    const float* Lw1 = (const float*)d_in[2];
    const float* Lb1 = (const float*)d_in[3];
    const float* Lw2 = (const float*)d_in[4];
    const float* Lb2 = (const float*)d_in[5];
    const float* Gw1 = (const float*)d_in[6];
    const float* Gb1 = (const float*)d_in[7];
    const float* Gw2 = (const float*)d_in[8];
    const float* Gb2 = (const float*)d_in[9];
    const float* uw  = (const float*)d_in[10];
    const float* ub  = (const float*)d_in[11];
    const float* Wuw = (const float*)d_in[12];
    const float* Wub = (const float*)d_in[13];
    const float* Huw = (const float*)d_in[14];
    const float* Hub = (const float*)d_in[15];
    const float* Msw = (const float*)d_in[16];
    const float* Msb = (const float*)d_in[17];
    const float* ow  = (const float*)d_in[18];
    const float* ob  = (const float*)d_in[19];
    const float* k1r = (const float*)d_in[20];
    const float* k1i = (const float*)d_in[21];
    const float* k2r = (const float*)d_in[22];
    const float* k2i = (const float*)d_in[23];

    float* A1 = (float*)d_ws;                 // 1,572,864 floats (6 MB)
    short* Tp = (short*)(A1 + 1572864);       // 2,097,152 shorts (4 MB)
    short* tab = Tp + 2097152;
    short* G1a  = tab;               // 1024
    short* L1a  = G1a + 1024;        // 1024
    short* G2T  = L1a + 1024;        // 2048
    short* L2T  = G2T + 2048;        // 2048
    short* WuT  = L2T + 2048;        // 1024
    short* HuT  = WuT + 1024;        // 1024
    short* owT  = HuT + 1024;        // 1024
    short* uwT  = owT + 1024;        // 1024
    short* MsA  = uwT + 1024;        // 512
    short* basisW  = MsA + 512;      // 8192
    short* basis2P = basisW + 8192;  // 8192
    short* basisH1 = basis2P + 8192; // 12288
    short* basisH3 = basisH1 + 12288;// 16384
    short* Kp   = basisH3 + 16384;   // 589824
    short* SBg  = Kp + 589824;       // 393216
    float* obP  = (float*)(SBg + 393216); // 32 floats

    float* outp = (float*)d_out;

    kern0<<<339, 256, 0, stream>>>(Lw1, Lb1, Lw2, Gw1, Gb1, Gw2, uw,
                                   Wuw, Huw, Msw, Msb, ow, ob, Wub,
                                   k1r, k1i, k2r, k2i,
                                   G1a, L1a, G2T, L2T, WuT, HuT, owT, uwT, MsA,
                                   basisW, basis2P, basisH1, basisH3, Kp, obP);
    kernAG<<<BB*256*2, 256, 0, stream>>>(x, kk, Lb2, ub, Gb2,
                                         L1a, L2T, G1a, G2T, uwT, MsA, basisW,
                                         A1, outp);
    kernC1<<<BB*12, 512, 0, stream>>>(A1, basisH1, Kp, SBg);
    kernC2<<<BB*16, 256, 0, stream>>>(basisH3, SBg, Hub, Tp);
    kernD<<<BB*256, 256, 0, stream>>>(obP, WuT, HuT, owT, basis2P, Tp, outp);
}

// Round 23
// 104.013 us; speedup vs baseline: 1.2475x; 1.2475x over previous
//
#include <hip/hip_runtime.h>
#include <hip/hip_bf16.h>
#include <math.h>

#define BB 8
#define NMODE 24

typedef __attribute__((ext_vector_type(8))) short bf16x8;
typedef __attribute__((ext_vector_type(4))) short bf16x4;
typedef __attribute__((ext_vector_type(4))) float f32x4;

#define MFMA32(a,b,c) __builtin_amdgcn_mfma_f32_16x16x32_bf16(a,b,c,0,0,0)

#if __has_builtin(__builtin_amdgcn_mfma_f32_16x16x16bf16_1k)
#define MFMA16(a,b,c) __builtin_amdgcn_mfma_f32_16x16x16bf16_1k(a,b,c,0,0,0)
#else
static __device__ __forceinline__ f32x4 MFMA16(bf16x4 a, bf16x4 b, f32x4 c){
    f32x4 d;
    asm("v_mfma_f32_16x16x16_bf16 %0, %1, %2, %3" : "=v"(d) : "v"(a), "v"(b), "v"(c));
    return d;
}
#endif

// packed f32->bf16 RNE via compiler intrinsic (memcpy, NOT bit_cast: round-4 lesson)
__device__ __forceinline__ unsigned pk2(float lo, float hi){
    __hip_bfloat162 h = __float22bfloat162_rn(make_float2(lo, hi));
    unsigned u; __builtin_memcpy(&u, &h, 4);
    return u;
}
__device__ __forceinline__ short f2b(float f){
    unsigned u = pk2(f, f);
    return (short)u;
}
__device__ __forceinline__ float b2f(short s){
    unsigned u = ((unsigned)(unsigned short)s) << 16;
    return __builtin_bit_cast(float, u);
}
__device__ __forceinline__ bf16x4 cvt4(f32x4 v){
    uint2 t; t.x = pk2(v[0], v[1]); t.y = pk2(v[2], v[3]);
    return __builtin_bit_cast(bf16x4, t);
}
__device__ __forceinline__ bf16x8 cvt8(float4 a, float4 b){
    uint4 t; t.x = pk2(a.x, a.y); t.y = pk2(a.z, a.w);
    t.z = pk2(b.x, b.y); t.w = pk2(b.z, b.w);
    return __builtin_bit_cast(bf16x8, t);
}
// tanh-gelu: v - v/(1+exp(2u)); exp2-based, ~8 VALU ops. NaN-safe.
__device__ __forceinline__ float gelu_f(float v) {
    float v2  = v * v;
    float arg = v * fmaf(0.10294294f, v2, 2.30220795f);
    float s   = __builtin_amdgcn_exp2f(arg);
    float rc  = __builtin_amdgcn_rcpf(1.0f + s);
    return v - v * rc;
}

// ======== kern0: precompute bf16 tables (Kp/basis sections split fine) ========
__global__ __launch_bounds__(256) void kern0(
    const float* __restrict__ Lw1, const float* __restrict__ Lb1, const float* __restrict__ Lw2,
    const float* __restrict__ Gw1, const float* __restrict__ Gb1, const float* __restrict__ Gw2,
    const float* __restrict__ uw,
    const float* __restrict__ Wuw, const float* __restrict__ Huw,
    const float* __restrict__ Msw, const float* __restrict__ Msb,
    const float* __restrict__ ow,  const float* __restrict__ ob,
    const float* __restrict__ Wub,
    const float* __restrict__ k1r, const float* __restrict__ k1i,
    const float* __restrict__ k2r, const float* __restrict__ k2i,
    short* __restrict__ G1a, short* __restrict__ L1a,
    short* __restrict__ G2T, short* __restrict__ L2T,
    short* __restrict__ WuT, short* __restrict__ HuT,
    short* __restrict__ owT, short* __restrict__ uwT, short* __restrict__ MsA,
    short* __restrict__ basisW, short* __restrict__ basis2P,
    short* __restrict__ basisH1, short* __restrict__ basisH3,
    short* __restrict__ Kp, float* __restrict__ obP)
{
    const int bid = blockIdx.x, t = threadIdx.x;
    const float tp = 6.28318530717958648f/256.f;
    if (bid == 0){
        for (int idx=t; idx<1024; idx+=256){
            int o = idx>>5, c = idx&31;
            WuT[o*32+c] = f2b(Wuw[c*32+o]);
        }
    } else if (bid == 1){
        for (int idx=t; idx<1024; idx+=256){
            int o = idx>>5, c = idx&31;
            HuT[o*32+c] = f2b(Huw[c*32+o]);
        }
    } else if (bid == 2){
        for (int idx=t; idx<1024; idx+=256){
            int hd = idx>>4, k2 = idx&15;
            G1a[idx] = f2b(k2<4 ? Gw1[k2*64+hd] : (k2==4 ? Gb1[hd] : 0.f));
            L1a[idx] = f2b(k2<4 ? Lw1[k2*64+hd] : (k2==4 ? Lb1[hd] : 0.f));
        }
    } else if (bid == 3){
        for (int idx=t; idx<2048; idx+=256){ int o=idx>>6, m=idx&63; G2T[idx]=f2b(Gw2[m*32+o]); }
    } else if (bid == 4){
        for (int idx=t; idx<2048; idx+=256){ int o=idx>>6, m=idx&63; L2T[idx]=f2b(Lw2[m*32+o]); }
    } else if (bid == 5){
        for (int idx=t; idx<1024; idx+=256){
            int o=idx>>5, c=idx&31;
            owT[idx]=f2b(ow[c*32+o]);
            uwT[idx]=f2b(uw[c*32+o]);
        }
    } else if (bid == 6){
        for (int idx=t; idx<512; idx+=256){
            int o=idx>>4, k2=idx&15;
            MsA[idx]=f2b(k2<4 ? Msw[k2*32+o] : (k2==4 ? Msb[o] : 0.f));
        }
        if (t < 32){
            float s = ob[t];
            for (int c=0;c<32;c++) s += Wub[c]*ow[c*32+t];
            obP[t] = s;
        }
    } else if (bid < 15){
        int base=(bid-7)*1024;
        for (int i=t; i<1024; i+=256){
            int idx=base+i; int m=idx>>8, w=idx&255;
            float v=0.f;
            if (m<12)       v = cosf(tp*(float)((m*w)&255));
            else if (m<24)  v = sinf(tp*(float)(((m-12)*w)&255));
            basisW[idx]=f2b(v);
        }
    } else if (bid < 23){
        int base=(bid-15)*1024;
        for (int i=t; i<1024; i+=256){
            int idx=base+i; int w=idx>>5, k=idx&31;
            float v=0.f;
            if (k<24){ int m=k>>1; float a=tp*(float)((m*w)&255); v=(k&1)? -sinf(a):cosf(a); }
            basis2P[idx]=f2b(v);
        }
    } else if (bid < 35){
        // basisH1: 12 blocks x 1024
        int base=(bid-23)*1024;
        for (int i=t; i<1024; i+=256){
            int idx=base+i; int m = idx>>8, h = idx&255;
            int mm = m % 24;
            int ia = (mm<12) ? mm : 232+mm;
            float a = tp*(float)((ia*h)&255);
            basisH1[idx] = f2b(m<24 ? cosf(a) : sinf(a));
        }
    } else if (bid < 51){
        // basisH3: 16 blocks x 1024
        int base=(bid-35)*1024;
        for (int i=t; i<1024; i+=256){
            int idx=base+i; int h = idx>>6, k = idx&63;
            float v = 0.f;
            if (k < 48){
                int mm = k % 24;
                int ia = (mm<12) ? mm : 232+mm;
                float a = tp*(float)((ia*h)&255);
                v = (k<24) ? cosf(a) : sinf(a);
            }
            basisH3[idx] = f2b(v);
        }
    } else {
        // Kp: 288 blocks x 1024 entries (fine split for gather-latency hiding)
        int base=(bid-51)*1024;
        for (int i=t; i<1024; i+=256){
            int pid = base + i;
            int o = pid & 31, c = (pid>>5) & 31;
            int rest = pid >> 10;
            int ii = rest % 24, jj = rest / 24;
            int iis = (ii<12) ? ii : ii-12;
            const float* wr = (ii<12) ? k1r : k2r;
            const float* wi = (ii<12) ? k1i : k2i;
            size_t widx = ((size_t)(c*32 + o)*12 + iis)*12 + jj;
            float sc = (jj==0 ? 1.f : 2.f) / 65536.f;
            Kp[2*pid]   = f2b(wr[widx] * sc);
            Kp[2*pid+1] = f2b(wi[widx] * sc);
        }
    }
}

// Forward layout in d_out per block bh (region 32 KB = 16384 shorts):
//   u slot s = nt*2+mt (0..7), G slot s = 8+nt*2+mt (8..15)
//   addr_shorts = bh*16384 + s*1024 + tid*4 (bf16x4/thread)

// ======== kernAG: role-split. blocks<NA: A-role; blocks>=NA: G-role ========
__global__ __launch_bounds__(256, 4) void kernAG(
    const float* __restrict__ x, const float* __restrict__ kk,
    const float* __restrict__ Lb2, const float* __restrict__ ubv,
    const float* __restrict__ Gb2,
    const short* __restrict__ L1a, const short* __restrict__ L2T,
    const short* __restrict__ G1a, const short* __restrict__ G2T,
    const short* __restrict__ uwT, const short* __restrict__ MsA,
    const short* __restrict__ basisW, float* __restrict__ A1,
    float* __restrict__ outw)
{
    __shared__ short vT[32*264];   // A-role only
    const int tid = threadIdx.x, l = tid&63, wv = tid>>6;
    const int q = l>>4, r = l&15;
    const f32x4 z4 = {0.f,0.f,0.f,0.f};

    if (blockIdx.x >= (unsigned)(BB*256)){
        // ---------------- G-role ----------------
        const int bh = blockIdx.x - BB*256;
        short* ug = (short*)outw + (size_t)bh*16384;

        bf16x4 ga[4], g2f[2][4];
        #pragma unroll
        for (int mt=0; mt<4; mt++) ga[mt] = *(const bf16x4*)(G1a + (r+16*mt)*16 + 4*q);
        #pragma unroll
        for (int mt=0; mt<2; mt++)
            #pragma unroll
            for (int ks=0; ks<4; ks++)
                g2f[mt][ks] = *(const bf16x4*)(G2T + (r+16*mt)*64 + 16*ks + 4*q);
        f32x4 gb2v[2];
        #pragma unroll
        for (int mt=0; mt<2; mt++) gb2v[mt] = *(const f32x4*)(Gb2 + 16*mt + 4*q);

        bf16x4 kB[4];
        #pragma unroll
        for (int nt=0; nt<4; nt++){
            const int p = wv*64 + nt*16 + r;
            bf16x4 t = {0,0,0,0};
            if (q==0){
                float4 k4 = *(const float4*)(kk + ((size_t)bh*256 + p)*4);
                uint2 pkk; pkk.x = pk2(k4.x, k4.y); pkk.y = pk2(k4.z, k4.w);
                t = __builtin_bit_cast(bf16x4, pkk);
            } else if (q==1){ t[0] = (short)0x3F80; }
            kB[nt] = t;
        }

        bf16x4 hidG[4][4];
        #pragma unroll
        for (int nt=0; nt<4; nt++)
            #pragma unroll
            for (int mt=0; mt<4; mt++){
                f32x4 acc = MFMA16(ga[mt], kB[nt], z4);
                f32x4 g;
                #pragma unroll
                for (int i=0;i<4;i++) g[i]=gelu_f(acc[i]);
                hidG[nt][mt] = cvt4(g);
            }

        #pragma unroll
        for (int nt=0; nt<4; nt++){
            #pragma unroll
            for (int mt=0; mt<2; mt++){
                f32x4 aG  = MFMA16(g2f[mt][0], hidG[nt][0], gb2v[mt]);
                f32x4 aG2 = MFMA16(g2f[mt][1], hidG[nt][1], z4);
                aG  = MFMA16(g2f[mt][2], hidG[nt][2], aG);
                aG2 = MFMA16(g2f[mt][3], hidG[nt][3], aG2);
                f32x4 gs;
                #pragma unroll
                for (int rg=0; rg<4; rg++) gs[rg] = aG[rg] + aG2[rg];
                *(bf16x4*)(ug + (8 + nt*2+mt)*1024 + tid*4) = cvt4(gs);
            }
        }
        return;
    }

    // ---------------- A-role ----------------
    const int bh = blockIdx.x, b = bh>>8, h = bh&255;
    short* ug = (short*)outw + (size_t)bh*16384;

    bf16x4 la[4], ma[2], l2f[2][4];
    bf16x8 ua8[2];
    #pragma unroll
    for (int mt=0; mt<4; mt++) la[mt] = *(const bf16x4*)(L1a + (r+16*mt)*16 + 4*q);
    #pragma unroll
    for (int mt=0; mt<2; mt++){
        ma[mt]  = *(const bf16x4*)(MsA + (r+16*mt)*16 + 4*q);
        ua8[mt] = *(const bf16x8*)(uwT + (r+16*mt)*32 + 8*q);
        #pragma unroll
        for (int ks=0; ks<4; ks++)
            l2f[mt][ks] = *(const bf16x4*)(L2T + (r+16*mt)*64 + 16*ks + 4*q);
    }
    f32x4 lb2v[2], ubv4[2];
    #pragma unroll
    for (int mt=0; mt<2; mt++){
        lb2v[mt] = *(const f32x4*)(Lb2 + 16*mt + 4*q);
        ubv4[mt] = *(const f32x4*)(ubv + 16*mt + 4*q);
    }

    #pragma unroll
    for (int nt=0; nt<4; nt++){
        const int p = wv*64 + nt*16 + r;
        const float* xp = x + ((size_t)bh*256 + p)*32 + 8*q;
        float4 x0 = *(const float4*)xp;
        float4 x1 = *(const float4*)(xp + 4);
        bf16x8 xB8 = cvt8(x0, x1);
        bf16x4 kB = {0,0,0,0};
        if (q==0){
            float4 k4 = *(const float4*)(kk + ((size_t)bh*256 + p)*4);
            uint2 pkk; pkk.x = pk2(k4.x, k4.y); pkk.y = pk2(k4.z, k4.w);
            kB = __builtin_bit_cast(bf16x4, pkk);
        } else if (q==1){ kB[0] = (short)0x3F80; }

        bf16x4 hidL[4];
        #pragma unroll
        for (int mt=0; mt<4; mt++){
            f32x4 accL = MFMA16(la[mt], kB, z4);
            f32x4 gl;
            #pragma unroll
            for (int i=0;i<4;i++) gl[i]=gelu_f(accL[i]);
            hidL[mt] = cvt4(gl);
        }
        #pragma unroll
        for (int mt=0; mt<2; mt++){
            f32x4 aU = MFMA32(ua8[mt], xB8, ubv4[mt]);
            // forward u (coalesced slot store)
            *(bf16x4*)(ug + (nt*2+mt)*1024 + tid*4) = cvt4(aU);
            f32x4 aM = MFMA16(ma[mt], kB, z4);
            f32x4 aL  = MFMA16(l2f[mt][0], hidL[0], lb2v[mt]);
            f32x4 aL2 = MFMA16(l2f[mt][1], hidL[1], z4);
            aL  = MFMA16(l2f[mt][2], hidL[2], aL);
            aL2 = MFMA16(l2f[mt][3], hidL[3], aL2);
            f32x4 vv;
            #pragma unroll
            for (int rg=0; rg<4; rg++) vv[rg] = (aL[rg]+aL2[rg]) * aU[rg] + aM[rg];
            bf16x4 vb = cvt4(vv);
            #pragma unroll
            for (int rg=0; rg<4; rg++)
                vT[(16*mt + 4*q + rg)*264 + p] = vb[rg];
        }
    }
    __syncthreads();

    // w-DFT
    const int mt2 = wv>>1, nt2 = wv&1;
    f32x4 accD = z4;
    #pragma unroll
    for (int ks=0; ks<8; ks++){
        bf16x8 av = *(const bf16x8*)(basisW + (r+16*mt2)*256 + 32*ks + 8*q);
        bf16x8 bv = *(const bf16x8*)(&vT[(r+16*nt2)*264 + 32*ks + 8*q]);
        accD = MFMA32(av, bv, accD);
    }
    #pragma unroll
    for (int rg=0; rg<4; rg++){
        int mode = 16*mt2 + 4*q + rg;
        int ch = r + 16*nt2;
        if (mode < 12)
            A1[((size_t)(b*12+mode)*256 + h)*64 + ch*2] = accD[rg];
        else if (mode < 24)
            A1[((size_t)(b*12+mode-12)*256 + h)*64 + ch*2 + 1] = -accD[rg];
    }
}

// ======== kernC1: per (b,j): LDS-transposed MFMA h-DFT + spectral multiply ========
__global__ __launch_bounds__(512) void kernC1(
    const float* __restrict__ A1, const short* __restrict__ basisH1,
    const short* __restrict__ Kp, short* __restrict__ SBg)
{
    __shared__ short AT[64*264];
    __shared__ float C1L[48*66];
    const int bj = blockIdx.x;
    const int j  = bj % 12;
    const int tid = threadIdx.x, l = tid&63;
    const int w = tid>>6;
    const int q = l>>4, r = l&15;
    const f32x4 z4 = {0.f,0.f,0.f,0.f};

    {
        const float* Ag = A1 + (size_t)bj*16384;
        for (int i = tid; i < 4096; i += 512){
            float4 v = *(const float4*)(Ag + i*4);
            int hh = (i*4) >> 6;
            int cc = (i*4) & 63;
            AT[(cc+0)*264 + hh] = f2b(v.x);
            AT[(cc+1)*264 + hh] = f2b(v.y);
            AT[(cc+2)*264 + hh] = f2b(v.z);
            AT[(cc+3)*264 + hh] = f2b(v.w);
        }
    }
    __syncthreads();

    {
        const int nt  = w & 3;
        const int nmt = (w < 4) ? 2 : 1;
        const int mt0 = (w < 4) ? 0 : 2;
        f32x4 acc[2] = {z4, z4};
        #pragma unroll
        for (int ks=0; ks<8; ks++){
            bf16x8 bv = *(const bf16x8*)(AT + (nt*16 + r)*264 + ks*32 + q*8);
            #pragma unroll
            for (int mi=0; mi<2; mi++){
                if (mi < nmt){
                    bf16x8 av = *(const bf16x8*)(basisH1 + (r + 16*(mt0+mi))*256 + ks*32 + q*8);
                    acc[mi] = MFMA32(av, bv, acc[mi]);
                }
            }
        }
        #pragma unroll
        for (int mi=0; mi<2; mi++){
            if (mi < nmt){
                #pragma unroll
                for (int rg=0; rg<4; rg++)
                    C1L[(16*(mt0+mi) + 4*q + rg)*66 + 16*nt + r] = acc[mi][rg];
            }
        }
    }
    __syncthreads();

    {
        const int o = tid & 31, g = tid >> 5;
        short* SB = SBg + (size_t)bj*4096;
        #pragma unroll
        for (int half=0; half<2; half++){
            int i = g + 16*half;
            if (i < 24){
                float Sre=0.f, Sim=0.f;
                const short* kp = Kp + ((size_t)(j*24 + i)*32)*64 + 2*o;
                #pragma unroll 4
                for (int c=0; c<32; c++){
                    float vr = C1L[i*66 + 2*c]     + C1L[(24+i)*66 + 2*c+1];
                    float vi = C1L[i*66 + 2*c + 1] - C1L[(24+i)*66 + 2*c];
                    short2 kv = *(const short2*)(kp + c*64);
                    float kr = b2f(kv.x), ki = b2f(kv.y);
                    Sre += vr*kr - vi*ki;
                    Sim += vr*ki + vi*kr;
                }
                SB[o*64 + i]           = f2b(Sre);
                SB[o*64 + 24 + i]      = f2b(-Sim);
                SB[2048 + o*64 + i]    = f2b(Sim);
                SB[2048 + o*64 + 24+i] = f2b(Sre);
            }
        }
        int o2 = (tid >> 4) & 31, kz = 48 + (tid & 15);
        SB[o2*64 + kz] = 0;
        SB[2048 + o2*64 + kz] = 0;
    }
}

// ======== kernC2: inverse h-DFT for ALL j, Hub folded into k=0, dense Tp dump ========
__global__ __launch_bounds__(256) void kernC2(
    const short* __restrict__ basisH3, const short* __restrict__ SBg,
    const float* __restrict__ Hub, short* __restrict__ Tp)
{
    __shared__ __align__(16) short Tt[16*1024];
    const int bid = blockIdx.x;
    const int b = bid >> 4, ht = bid & 15;
    const int tid = threadIdx.x, l = tid&63, w = tid>>6;
    const int q = l>>4, r = l&15;
    const f32x4 z4 = {0.f,0.f,0.f,0.f};

    for (int idx = tid; idx < 512; idx += 256){
        int hh = idx >> 5, o = idx & 31;
        #pragma unroll
        for (int kkz=0; kkz<8; kkz++) Tt[(hh*32+o)*32 + 24 + kkz] = 0;
    }

    bf16x8 af[2];
    #pragma unroll
    for (int ks=0; ks<2; ks++)
        af[ks] = *(const bf16x8*)(basisH3 + (ht*16 + r)*64 + ks*32 + q*8);

    #pragma unroll
    for (int jj=0; jj<3; jj++){
        int j = w*3 + jj;
        const short* SB = SBg + (size_t)(b*12 + j)*4096;
        #pragma unroll
        for (int nt=0; nt<2; nt++){
            f32x4 aRe = z4, aIm = z4;
            #pragma unroll
            for (int ks=0; ks<2; ks++){
                bf16x8 b1 = *(const bf16x8*)(SB + (16*nt + r)*64 + ks*32 + q*8);
                bf16x8 b2 = *(const bf16x8*)(SB + 2048 + (16*nt + r)*64 + ks*32 + q*8);
                aRe = MFMA32(af[ks], b1, aRe);
                aIm = MFMA32(af[ks], b2, aIm);
            }
            if (j == 0){
                float hb = Hub[16*nt + r];
                #pragma unroll
                for (int rg=0; rg<4; rg++) aRe[rg] -= hb;
            }
            #pragma unroll
            for (int rg=0; rg<4; rg++){
                int hl = 4*q + rg, o = 16*nt + r;
                *(unsigned*)&Tt[(hl*32 + o)*32 + 2*j] = pk2(aRe[rg], aIm[rg]);
            }
        }
    }
    __syncthreads();

    short* dst = Tp + (size_t)(b*256 + ht*16)*1024;
    #pragma unroll
    for (int it=0; it<8; it++){
        int off = (tid + it*256)*8;
        *(int4*)(dst + off) = *(const int4*)&Tt[off];
    }
}

// ======== kernD: consumer — u and G from d_out slots ========
__global__ __launch_bounds__(256, 4) void kernD(
    const float* __restrict__ obP,
    const short* __restrict__ WuT, const short* __restrict__ HuT,
    const short* __restrict__ owT, const short* __restrict__ basis2P,
    const short* __restrict__ Tp, float* out)
{
    const int bh = blockIdx.x;
    const int tid = threadIdx.x, l = tid&63, wv = tid>>6;
    const int q = l>>4, r = l&15;
    const f32x4 z4 = {0.f,0.f,0.f,0.f};
    const short* ug = (const short*)out + (size_t)bh*16384;

    // ---- pre-barrier: u+G slot loads (alias out!) + fragments ----
    bf16x4 uB[4][2], Gf[4][2];
    bf16x8 bb8[4];
    #pragma unroll
    for (int nt=0; nt<4; nt++){
        const int p = wv*64 + nt*16 + r;
        #pragma unroll
        for (int ks=0; ks<2; ks++){
            uB[nt][ks] = *(const bf16x4*)(ug + (nt*2+ks)*1024 + tid*4);
            Gf[nt][ks] = *(const bf16x4*)(ug + (8 + nt*2+ks)*1024 + tid*4);
        }
        bb8[nt] = *(const bf16x8*)(basis2P + p*32 + 8*q);
    }
    bf16x8 tp8[2];
    bf16x4 wuf[2][2], huf[2][2], owf[2][2];
    f32x4 obv2[2];
    #pragma unroll
    for (int mt=0; mt<2; mt++){
        tp8[mt] = *(const bf16x8*)(Tp + (size_t)bh*1024 + (r+16*mt)*32 + 8*q);
        #pragma unroll
        for (int ks=0; ks<2; ks++){
            wuf[mt][ks] = *(const bf16x4*)(WuT + (r+16*mt)*32 + 16*ks + 4*q);
            huf[mt][ks] = *(const bf16x4*)(HuT + (r+16*mt)*32 + 16*ks + 4*q);
            owf[mt][ks] = *(const bf16x4*)(owT + (r+16*mt)*32 + 16*ks + 4*q);
        }
        obv2[mt] = *(const f32x4*)(obP + 16*mt + 4*q);
    }
    __syncthreads();   // drains loads before any out-store

    #pragma unroll
    for (int nt=0; nt<4; nt++){
        const int p = wv*64 + nt*16 + r;
        bf16x4 bornB[2];
        #pragma unroll
        for (int mt=0; mt<2; mt++){
            f32x4 aFv = MFMA32(tp8[mt], bb8[nt], z4);          // includes -Hub fold
            f32x4 aHu = MFMA16(huf[mt][0], uB[nt][0], z4);
            aHu = MFMA16(huf[mt][1], uB[nt][1], aHu);
            f32x4 aW  = MFMA16(wuf[mt][0], uB[nt][0], z4);
            aW  = MFMA16(wuf[mt][1], uB[nt][1], aW);
            f32x4 brn;
            #pragma unroll
            for (int rg=0; rg<4; rg++)
                brn[rg] = aW[rg] - b2f(Gf[nt][mt][rg]) * (aHu[rg] - aFv[rg]);
            bornB[mt] = cvt4(brn);
        }
        #pragma unroll
        for (int mt=0; mt<2; mt++){
            f32x4 aO = MFMA16(owf[mt][0], bornB[0], obv2[mt]); // includes Wub@ow fold
            aO = MFMA16(owf[mt][1], bornB[1], aO);
            float4 res;
            res.x = gelu_f(aO[0]);
            res.y = gelu_f(aO[1]);
            res.z = gelu_f(aO[2]);
            res.w = gelu_f(aO[3]);
            *(float4*)(out + ((size_t)bh*256 + p)*32 + 16*mt + 4*q) = res;
        }
    }
}

extern "C" void kernel_launch(void* const* d_in, const int* in_sizes, int n_in,
                              void* d_out, int out_size, void* d_ws, size_t ws_size,
                              hipStream_t stream)
{
    const float* x   = (const float*)d_in[0];
    const float* kk  = (const float*)d_in[1];
    const float* Lw1 = (const float*)d_in[2];
    const float* Lb1 = (const float*)d_in[3];
    const float* Lw2 = (const float*)d_in[4];
    const float* Lb2 = (const float*)d_in[5];
    const float* Gw1 = (const float*)d_in[6];
    const float* Gb1 = (const float*)d_in[7];
    const float* Gw2 = (const float*)d_in[8];
    const float* Gb2 = (const float*)d_in[9];
    const float* uw  = (const float*)d_in[10];
    const float* ub  = (const float*)d_in[11];
    const float* Wuw = (const float*)d_in[12];
    const float* Wub = (const float*)d_in[13];
    const float* Huw = (const float*)d_in[14];
    const float* Hub = (const float*)d_in[15];
    const float* Msw = (const float*)d_in[16];
    const float* Msb = (const float*)d_in[17];
    const float* ow  = (const float*)d_in[18];
    const float* ob  = (const float*)d_in[19];
    const float* k1r = (const float*)d_in[20];
    const float* k1i = (const float*)d_in[21];
    const float* k2r = (const float*)d_in[22];
    const float* k2i = (const float*)d_in[23];

    float* A1 = (float*)d_ws;                 // 1,572,864 floats (6 MB)
    short* Tp = (short*)(A1 + 1572864);       // 2,097,152 shorts (4 MB)
    short* tab = Tp + 2097152;
    short* G1a  = tab;               // 1024
    short* L1a  = G1a + 1024;        // 1024
    short* G2T  = L1a + 1024;        // 2048
    short* L2T  = G2T + 2048;        // 2048
    short* WuT  = L2T + 2048;        // 1024
    short* HuT  = WuT + 1024;        // 1024
    short* owT  = HuT + 1024;        // 1024
    short* uwT  = owT + 1024;        // 1024
    short* MsA  = uwT + 1024;        // 512
    short* basisW  = MsA + 512;      // 8192
    short* basis2P = basisW + 8192;  // 8192
    short* basisH1 = basis2P + 8192; // 12288
    short* basisH3 = basisH1 + 12288;// 16384
    short* Kp   = basisH3 + 16384;   // 589824
    short* SBg  = Kp + 589824;       // 393216
    float* obP  = (float*)(SBg + 393216); // 32 floats

    float* outp = (float*)d_out;

    kern0<<<339, 256, 0, stream>>>(Lw1, Lb1, Lw2, Gw1, Gb1, Gw2, uw,
                                   Wuw, Huw, Msw, Msb, ow, ob, Wub,
                                   k1r, k1i, k2r, k2i,
                                   G1a, L1a, G2T, L2T, WuT, HuT, owT, uwT, MsA,
                                   basisW, basis2P, basisH1, basisH3, Kp, obP);
    kernAG<<<BB*256*2, 256, 0, stream>>>(x, kk, Lb2, ub, Gb2,
                                         L1a, L2T, G1a, G2T, uwT, MsA, basisW,
                                         A1, outp);
    kernC1<<<BB*12, 512, 0, stream>>>(A1, basisH1, Kp, SBg);
    kernC2<<<BB*16, 256, 0, stream>>>(basisH3, SBg, Hub, Tp);
    kernD<<<BB*256, 256, 0, stream>>>(obP, WuT, HuT, owT, basis2P, Tp, outp);
}